// Round 1
// baseline (714.055 us; speedup 1.0000x reference)
//
#include <hip/hip_runtime.h>

// SGConv: K=3 hops of \hat{A} x (symmetric gcn_norm with self-loops), then Linear.
// N=100000, E=1600000, F_in=32, F_out=64 (F dims hardcoded; N,E derived from sizes).

#define F_IN 32
#define F_OUT 64
#define K_HOPS 3

__global__ void k_init_deg(float* __restrict__ deg, int N) {
    int i = blockIdx.x * blockDim.x + threadIdx.x;
    if (i < N) deg[i] = 1.0f;  // self-loop contributes 1 to in-degree
}

__global__ void k_count_deg(const int* __restrict__ dst, float* deg, int E) {
    int e = blockIdx.x * blockDim.x + threadIdx.x;
    if (e < E) atomicAdd(&deg[dst[e]], 1.0f);
}

__global__ void k_rsqrt(float* __restrict__ deg, int N) {
    int i = blockIdx.x * blockDim.x + threadIdx.x;
    if (i < N) deg[i] = rsqrtf(deg[i]);  // deg >= 1 always (self-loop), no zero case
}

// h_new[i] = dinv[i]^2 * h_cur[i]  (the self-loop message), full init of h_new.
__global__ void k_hop_init(const float* __restrict__ hcur, const float* __restrict__ dinv,
                           float* __restrict__ hnew, int NF) {
    int t = blockIdx.x * blockDim.x + threadIdx.x;
    if (t < NF) {
        int i = t >> 5;  // F_IN = 32
        float di = dinv[i];
        hnew[t] = di * di * hcur[t];
    }
}

// One thread per (edge, feature): h_new[dst] += dinv[src]*dinv[dst] * h_cur[src].
// Lanes 0..31 of a half-wave share an edge -> coalesced row read, consecutive-address atomics.
__global__ void k_hop_scatter(const int* __restrict__ ei, const float* __restrict__ dinv,
                              const float* __restrict__ hcur, float* hnew, int E) {
    int t = blockIdx.x * blockDim.x + threadIdx.x;
    if (t < E * F_IN) {
        int e = t >> 5;
        int f = t & 31;
        int s = ei[e];       // edge_index[0][e]
        int d = ei[E + e];   // edge_index[1][e]
        float w = dinv[s] * dinv[d];
        atomicAdd(&hnew[d * F_IN + f], w * hcur[s * F_IN + f]);
    }
}

// out[n][o] = b[o] + sum_f h[n][f] * W[o][f]   (W is [F_OUT, F_IN] row-major)
// Block = 256 threads = 4 nodes x 64 outputs. W staged in LDS with +1 pad
// (bank = (o+f)%32 -> only 2-way aliasing across the 64-lane wave = free).
__global__ __launch_bounds__(256) void k_linear(const float* __restrict__ h,
                                                const float* __restrict__ W,
                                                const float* __restrict__ b,
                                                float* __restrict__ out, int N) {
    __shared__ float Wl[F_OUT][F_IN + 1];
    __shared__ float hl[4][F_IN];
    int tid = threadIdx.x;
    for (int idx = tid; idx < F_OUT * F_IN; idx += 256) {
        Wl[idx >> 5][idx & 31] = W[idx];
    }
    int node0 = blockIdx.x * 4;
    if (tid < 4 * F_IN) {
        int n = tid >> 5, f = tid & 31;
        int node = node0 + n;
        hl[n][f] = (node < N) ? h[node * F_IN + f] : 0.0f;
    }
    __syncthreads();
    int n = tid >> 6;   // 0..3
    int o = tid & 63;   // 0..63
    int node = node0 + n;
    if (node < N) {
        float acc = b[o];
#pragma unroll
        for (int f = 0; f < F_IN; ++f) acc += hl[n][f] * Wl[o][f];
        out[node * F_OUT + o] = acc;
    }
}

extern "C" void kernel_launch(void* const* d_in, const int* in_sizes, int n_in,
                              void* d_out, int out_size, void* d_ws, size_t ws_size,
                              hipStream_t stream) {
    const float* x  = (const float*)d_in[0];
    const int*   ei = (const int*)d_in[1];   // [2, E] int32, row-major: src then dst
    const float* W  = (const float*)d_in[2]; // [64, 32]
    const float* b  = (const float*)d_in[3]; // [64]
    float* out = (float*)d_out;              // [N, 64] fp32

    const int N = in_sizes[0] / F_IN;
    const int E = in_sizes[1] / 2;
    const int NF = N * F_IN;
    const int EF = E * F_IN;

    // Workspace: deg/dinv (N floats) | hA (N*32 floats). hB aliases d_out's
    // first N*32 floats (fully consumed before k_linear overwrites d_out).
    float* deg = (float*)d_ws;
    float* hA  = deg + N;
    float* hB  = out;

    const int B = 256;
    dim3 blk(B);

    // --- degree + dinv ---
    k_init_deg<<<dim3((N + B - 1) / B), blk, 0, stream>>>(deg, N);
    k_count_deg<<<dim3((E + B - 1) / B), blk, 0, stream>>>(ei + E, deg, E);
    k_rsqrt<<<dim3((N + B - 1) / B), blk, 0, stream>>>(deg, N);

    dim3 gNF((NF + B - 1) / B);
    dim3 gEF((EF + B - 1) / B);

    // hop 1: x -> hA
    k_hop_init<<<gNF, blk, 0, stream>>>(x, deg, hA, NF);
    k_hop_scatter<<<gEF, blk, 0, stream>>>(ei, deg, x, hA, E);
    // hop 2: hA -> hB
    k_hop_init<<<gNF, blk, 0, stream>>>(hA, deg, hB, NF);
    k_hop_scatter<<<gEF, blk, 0, stream>>>(ei, deg, hA, hB, E);
    // hop 3: hB -> hA
    k_hop_init<<<gNF, blk, 0, stream>>>(hB, deg, hA, NF);
    k_hop_scatter<<<gEF, blk, 0, stream>>>(ei, deg, hB, hA, E);

    // linear: hA @ W^T + b -> out
    k_linear<<<dim3((N + 3) / 4), blk, 0, stream>>>(hA, W, b, out, N);
}

// Round 2
// 354.145 us; speedup vs baseline: 2.0163x; 2.0163x over previous
//
#include <hip/hip_runtime.h>

// SGConv: K=3 hops of \hat{A} x (symmetric gcn_norm w/ self-loops), then Linear.
// N=100000, E=1600000, F_in=32, F_out=64.
// Round 2: CSR-by-dst build + atomic-free gather hops (round 1 showed 200MB/hop
// of HBM atomic write-through; gather keeps h in L3 and writes 12.8MB streaming).

#define F_IN 32
#define F_OUT 64
#define SCAN_B 256

typedef float f4 __attribute__((ext_vector_type(4)));

__global__ void k_count_deg(const int* __restrict__ dst, int* deg, int E) {
    int e = blockIdx.x * blockDim.x + threadIdx.x;
    if (e < E) atomicAdd(&deg[dst[e]], 1);
}

__global__ void k_dinv(const int* __restrict__ deg, float* __restrict__ dinv, int N) {
    int i = blockIdx.x * blockDim.x + threadIdx.x;
    if (i < N) dinv[i] = rsqrtf(1.0f + (float)deg[i]);  // +1 self-loop
}

// Per-block inclusive scan of deg -> rp[i+1]; block totals -> bsum.
__global__ __launch_bounds__(SCAN_B) void k_scan_block(const int* __restrict__ deg,
                                                       int* __restrict__ rp,
                                                       int* __restrict__ bsum, int N) {
    __shared__ int s[SCAN_B];
    int tid = threadIdx.x;
    int i = blockIdx.x * SCAN_B + tid;
    int v = (i < N) ? deg[i] : 0;
    s[tid] = v;
    __syncthreads();
    for (int off = 1; off < SCAN_B; off <<= 1) {
        int t = (tid >= off) ? s[tid - off] : 0;
        __syncthreads();
        s[tid] += t;
        __syncthreads();
    }
    if (i < N) rp[i + 1] = s[tid];
    if (tid == SCAN_B - 1) bsum[blockIdx.x] = s[tid];
}

// Single-block exclusive scan of the block sums (nb <= 512).
__global__ __launch_bounds__(512) void k_scan_bsums(int* __restrict__ bsum, int nb) {
    __shared__ int s[512];
    int tid = threadIdx.x;
    int v = (tid < nb) ? bsum[tid] : 0;
    s[tid] = v;
    __syncthreads();
    for (int off = 1; off < 512; off <<= 1) {
        int t = (tid >= off) ? s[tid - off] : 0;
        __syncthreads();
        s[tid] += t;
        __syncthreads();
    }
    if (tid < nb) bsum[tid] = s[tid] - v;  // exclusive
}

__global__ void k_scan_final(int* __restrict__ rp, const int* __restrict__ bsum, int N) {
    int i = blockIdx.x * blockDim.x + threadIdx.x;
    if (i == 0) rp[0] = 0;
    if (i < N) rp[i + 1] += bsum[i >> 8];  // SCAN_B == 256
}

// Scatter edges into CSR slots; precompute edge weight dinv[s]*dinv[d].
__global__ void k_fill(const int* __restrict__ ei, const int* __restrict__ rp,
                       int* tmp, const float* __restrict__ dinv,
                       int* __restrict__ col, float* __restrict__ w, int E) {
    int e = blockIdx.x * blockDim.x + threadIdx.x;
    if (e < E) {
        int s = ei[e];
        int d = ei[E + e];
        int slot = rp[d] + atomicAdd(&tmp[d], 1);
        col[slot] = s;
        w[slot] = dinv[s] * dinv[d];
    }
}

// Gather hop: 8 lanes (float4 each) per node row. No atomics.
// acc starts with the self-loop term dinv[n]^2 * h[n].
__global__ __launch_bounds__(256) void k_hop_gather(const int* __restrict__ rp,
                                                    const int* __restrict__ col,
                                                    const float* __restrict__ w,
                                                    const float* __restrict__ dinv,
                                                    const f4* __restrict__ hin,
                                                    f4* __restrict__ hout, int N) {
    int t = blockIdx.x * blockDim.x + threadIdx.x;
    int n = t >> 3;       // node
    int q = t & 7;        // which float4 of the 32-float row
    if (n >= N) return;
    float di = dinv[n];
    f4 acc = (di * di) * hin[n * 8 + q];
    int e0 = rp[n], e1 = rp[n + 1];
    int e = e0;
    for (; e + 1 < e1; e += 2) {
        int s0 = col[e], s1 = col[e + 1];
        float w0 = w[e], w1 = w[e + 1];
        f4 h0 = hin[s0 * 8 + q];
        f4 h1 = hin[s1 * 8 + q];
        acc += w0 * h0;
        acc += w1 * h1;
    }
    if (e < e1) acc += w[e] * hin[col[e] * 8 + q];
    hout[n * 8 + q] = acc;
}

// out[n][o] = b[o] + sum_f h[n][f] * W[o][f]
__global__ __launch_bounds__(256) void k_linear(const float* __restrict__ h,
                                                const float* __restrict__ W,
                                                const float* __restrict__ b,
                                                float* __restrict__ out, int N) {
    __shared__ float Wl[F_OUT][F_IN + 1];
    __shared__ float hl[4][F_IN];
    int tid = threadIdx.x;
    for (int idx = tid; idx < F_OUT * F_IN; idx += 256) {
        Wl[idx >> 5][idx & 31] = W[idx];
    }
    int node0 = blockIdx.x * 4;
    if (tid < 4 * F_IN) {
        int n = tid >> 5, f = tid & 31;
        int node = node0 + n;
        hl[n][f] = (node < N) ? h[node * F_IN + f] : 0.0f;
    }
    __syncthreads();
    int n = tid >> 6;
    int o = tid & 63;
    int node = node0 + n;
    if (node < N) {
        float acc = b[o];
#pragma unroll
        for (int f = 0; f < F_IN; ++f) acc += hl[n][f] * Wl[o][f];
        out[node * F_OUT + o] = acc;
    }
}

extern "C" void kernel_launch(void* const* d_in, const int* in_sizes, int n_in,
                              void* d_out, int out_size, void* d_ws, size_t ws_size,
                              hipStream_t stream) {
    const float* x  = (const float*)d_in[0];
    const int*   ei = (const int*)d_in[1];   // [2,E] int32: src row then dst row
    const float* W  = (const float*)d_in[2];
    const float* b  = (const float*)d_in[3];
    float* out = (float*)d_out;

    const int N = in_sizes[0] / F_IN;
    const int E = in_sizes[1] / 2;
    const int nb = (N + SCAN_B - 1) / SCAN_B;  // 391 <= 512

    // d_ws layout: deg(N int) | tmp(N int) | rp(N+1 int) | dinv(N f) | bsum(nb) | hA(N*32 f)
    int*   deg  = (int*)d_ws;
    int*   tmp  = deg + N;
    int*   rp   = tmp + N;
    float* dinv = (float*)(rp + N + 1);
    int*   bsum = (int*)(dinv + N);
    float* hA   = (float*)(((uintptr_t)(bsum + nb) + 255) & ~(uintptr_t)255);

    // d_out as scratch until k_linear: hB(N*32 f) | col(E int) | w(E f) = exactly N*64 f
    float* hB  = out;
    int*   col = (int*)(out + N * F_IN);
    float* w   = (float*)(col + E);

    const int B = 256;
    dim3 blk(B);
    dim3 gN((N + B - 1) / B), gE((E + B - 1) / B);

    hipMemsetAsync(deg, 0, (size_t)N * sizeof(int), stream);
    hipMemsetAsync(tmp, 0, (size_t)N * sizeof(int), stream);

    // CSR build
    k_count_deg<<<gE, blk, 0, stream>>>(ei + E, deg, E);
    k_dinv<<<gN, blk, 0, stream>>>(deg, dinv, N);
    k_scan_block<<<dim3(nb), dim3(SCAN_B), 0, stream>>>(deg, rp, bsum, N);
    k_scan_bsums<<<dim3(1), dim3(512), 0, stream>>>(bsum, nb);
    k_scan_final<<<gN, blk, 0, stream>>>(rp, bsum, N);
    k_fill<<<gE, blk, 0, stream>>>(ei, rp, tmp, dinv, col, w, E);

    // 3 gather hops (8 threads per node row)
    dim3 gHop((N * 8 + B - 1) / B);
    k_hop_gather<<<gHop, blk, 0, stream>>>(rp, col, w, dinv, (const f4*)x,  (f4*)hA, N);
    k_hop_gather<<<gHop, blk, 0, stream>>>(rp, col, w, dinv, (const f4*)hA, (f4*)hB, N);
    k_hop_gather<<<gHop, blk, 0, stream>>>(rp, col, w, dinv, (const f4*)hB, (f4*)hA, N);

    // linear (overwrites d_out incl. the col/w scratch — hA is in d_ws)
    k_linear<<<dim3((N + 3) / 4), blk, 0, stream>>>(hA, W, b, out, N);
}